// Round 1
// baseline (250.514 us; speedup 1.0000x reference)
//
#include <hip/hip_runtime.h>
#include <hip/hip_bf16.h>

typedef unsigned short ushort_t;

#define N_IMG 32
#define C_IN  128
#define C_OUT 256
#define H_SZ  56
#define W_SZ  56
#define HW_SZ (H_SZ * W_SZ)        // 3136
#define K_TOT (C_IN * 9)           // 1152
#define SP_TOT (N_IMG * HW_SZ)     // 100352

typedef __attribute__((ext_vector_type(8))) short bf16x8;
typedef __attribute__((ext_vector_type(4))) float floatx4;

__device__ __forceinline__ void gl_lds16(const ushort_t* g, ushort_t* l) {
  // 16B per lane, LDS dest = wave-uniform base + lane*16
  __builtin_amdgcn_global_load_lds(
      (const __attribute__((address_space(1))) void*)g,
      (__attribute__((address_space(3))) void*)l, 16, 0, 0);
}

__device__ __forceinline__ ushort_t f2bf(float f) {
  __hip_bfloat16 b = __float2bfloat16(f);
  return *reinterpret_cast<ushort_t*>(&b);
}

// w_q (int32 values in {-1,0,1}, layout [co][c][kh][kw]) -> w_t bf16 [co][tap][c]
// also zeroes the 256B zero-page used for conv padding.
__global__ void wtrans_kernel(const int* __restrict__ wq, ushort_t* __restrict__ wt,
                              ushort_t* __restrict__ zeros) {
  int tid = threadIdx.x;
  if (blockIdx.x == 0 && tid < 128) zeros[tid] = 0;
  int idx = blockIdx.x * 256 + tid;
  if (idx >= C_OUT * K_TOT) return;
  int co = idx / K_TOT;
  int k  = idx - co * K_TOT;
  int tap = k >> 7;          // k = tap*128 + c
  int c   = k & 127;
  int kh = tap / 3, kw = tap - kh * 3;
  int v = wq[((co * C_IN + c) * 3 + kh) * 3 + kw];
  wt[idx] = f2bf((float)v);
}

// x fp32 NCHW -> x_t bf16 NHWC, LDS transpose per (n,h) row
__global__ void xtrans_kernel(const float* __restrict__ x, ushort_t* __restrict__ xt) {
  __shared__ float tile[C_IN * W_SZ];   // 28672 B
  int b = blockIdx.x;                   // n*56 + h
  int n = b / H_SZ, h = b - n * H_SZ;
  int tid = threadIdx.x;
  const float* xbase = x + (size_t)n * C_IN * HW_SZ + h * W_SZ;
  for (int idx = tid; idx < C_IN * W_SZ; idx += 256) {
    int c = idx / W_SZ, w = idx - c * W_SZ;
    tile[idx] = xbase[(size_t)c * HW_SZ + w];   // coalesced along w
  }
  __syncthreads();
  ushort_t* obase = xt + (size_t)b * W_SZ * C_IN;
  for (int idx = tid; idx < W_SZ * (C_IN / 2); idx += 256) {
    int w  = idx >> 6;            // /64
    int ci = (idx & 63) * 2;
    unsigned int p = (unsigned int)f2bf(tile[ci * W_SZ + w]) |
                     ((unsigned int)f2bf(tile[(ci + 1) * W_SZ + w]) << 16);
    *(unsigned int*)&obase[(size_t)w * C_IN + ci] = p;   // contiguous along c
  }
}

// Implicit-GEMM conv: C[co][sp] = sum_k A[co][k] * B[k][sp], k = tap*128 + c
// A = w_t[co][k] (bf16, k contiguous), B gathered from x_t NHWC (k contiguous = c)
__global__ __launch_bounds__(256) void bitconv_kernel(
    const ushort_t* __restrict__ wt, const ushort_t* __restrict__ xt,
    const ushort_t* __restrict__ zeros,
    const float* __restrict__ s, const float* __restrict__ bias,
    float* __restrict__ out) {
  __shared__ ushort_t As[128 * 32];   // [co_local][k_local], 64B rows
  __shared__ ushort_t Bs[128 * 32];   // [sp_local][k_local]

  int bid = blockIdx.x;
  int co0 = (bid & 1) * 128;          // co-half fastest: adjacent blocks share B gather in L2
  int sp0 = (bid >> 1) * 128;

  int tid  = threadIdx.x;
  int lane = tid & 63;
  int wid  = tid >> 6;
  int l15  = lane & 15;
  int quad = lane >> 4;
  int lrow = lane >> 2;               // 0..15
  int lk8  = (lane & 3) * 8;          // 0,8,16,24
  int wave_m = (wid >> 1) * 64;
  int wave_n = (wid & 1) * 64;

  // A staging sources: wave stages co rows [wid*32, wid*32+32)
  const ushort_t* a_src[2];
  ushort_t* a_dst[2];
#pragma unroll
  for (int i = 0; i < 2; ++i) {
    int arow = wid * 32 + i * 16 + lrow;
    a_src[i] = wt + (size_t)(co0 + arow) * K_TOT + lk8;
    a_dst[i] = &As[(wid * 32 + i * 16) * 32];
  }

  // B rows: decompose spatial index once per lane
  int bh[2], bw[2];
  const ushort_t* b_img[2];
  ushort_t* b_dst[2];
#pragma unroll
  for (int i = 0; i < 2; ++i) {
    int sp   = sp0 + wid * 32 + i * 16 + lrow;
    int nimg = sp / HW_SZ;
    int rem  = sp - nimg * HW_SZ;
    bh[i] = rem / W_SZ;
    bw[i] = rem - bh[i] * W_SZ;
    b_img[i] = xt + (size_t)nimg * HW_SZ * C_IN;
    b_dst[i] = &Bs[(wid * 32 + i * 16) * 32];
  }

  floatx4 acc[4][4];
#pragma unroll
  for (int mi = 0; mi < 4; ++mi)
#pragma unroll
    for (int ni = 0; ni < 4; ++ni)
      acc[mi][ni] = (floatx4){0.f, 0.f, 0.f, 0.f};

  for (int tap = 0; tap < 9; ++tap) {
    int dh = tap / 3 - 1;
    int dw = tap - (dh + 1) * 3 - 1;
    const ushort_t* bsrc[2];
#pragma unroll
    for (int i = 0; i < 2; ++i) {
      int hh2 = bh[i] + dh, ww2 = bw[i] + dw;
      bool valid = (hh2 >= 0) & (hh2 < H_SZ) & (ww2 >= 0) & (ww2 < W_SZ);
      bsrc[i] = valid ? (b_img[i] + (size_t)(hh2 * W_SZ + ww2) * C_IN + lk8)
                      : (zeros + lk8);
    }
    int ktap = tap * C_IN;
#pragma unroll
    for (int c0 = 0; c0 < C_IN; c0 += 32) {
#pragma unroll
      for (int i = 0; i < 2; ++i) {
        gl_lds16(a_src[i] + ktap + c0, a_dst[i]);
        gl_lds16(bsrc[i] + c0, b_dst[i]);
      }
      __syncthreads();
      bf16x8 af[4], bfv[4];
#pragma unroll
      for (int mi = 0; mi < 4; ++mi)
        af[mi] = *(const bf16x8*)&As[(wave_m + mi * 16 + l15) * 32 + quad * 8];
#pragma unroll
      for (int ni = 0; ni < 4; ++ni)
        bfv[ni] = *(const bf16x8*)&Bs[(wave_n + ni * 16 + l15) * 32 + quad * 8];
#pragma unroll
      for (int mi = 0; mi < 4; ++mi)
#pragma unroll
        for (int ni = 0; ni < 4; ++ni)
          acc[mi][ni] = __builtin_amdgcn_mfma_f32_16x16x32_bf16(
              af[mi], bfv[ni], acc[mi][ni], 0, 0, 0);
      __syncthreads();
    }
  }

  // Epilogue: y = acc*s[co] + bias[co]; C/D layout col(sp)=lane&15, row(co)=quad*4+reg
  int spl_[4], nimg_[4];
#pragma unroll
  for (int ni = 0; ni < 4; ++ni) {
    int sp = sp0 + wave_n + ni * 16 + l15;
    int nimg = sp / HW_SZ;
    nimg_[ni] = nimg;
    spl_[ni]  = sp - nimg * HW_SZ;
  }
#pragma unroll
  for (int mi = 0; mi < 4; ++mi) {
#pragma unroll
    for (int r = 0; r < 4; ++r) {
      int co = co0 + wave_m + mi * 16 + quad * 4 + r;
      float sv = s[co];
      float bv = bias[co];
#pragma unroll
      for (int ni = 0; ni < 4; ++ni) {
        out[((size_t)nimg_[ni] * C_OUT + co) * HW_SZ + spl_[ni]] =
            acc[mi][ni][r] * sv + bv;
      }
    }
  }
}

extern "C" void kernel_launch(void* const* d_in, const int* in_sizes, int n_in,
                              void* d_out, int out_size, void* d_ws, size_t ws_size,
                              hipStream_t stream) {
  const float* x    = (const float*)d_in[0];
  const int*   wq   = (const int*)d_in[1];    // int per harness convention
  const float* s    = (const float*)d_in[2];
  const float* bias = (const float*)d_in[3];
  float* out = (float*)d_out;

  char* ws = (char*)d_ws;
  ushort_t* zeros = (ushort_t*)ws;                       // 256 B zero page
  ushort_t* wt    = (ushort_t*)(ws + 256);               // 589,824 B
  ushort_t* xt    = (ushort_t*)(ws + 590080);            // 25,690,112 B

  hipLaunchKernelGGL(wtrans_kernel, dim3((C_OUT * K_TOT) / 256), dim3(256), 0, stream,
                     wq, wt, zeros);
  hipLaunchKernelGGL(xtrans_kernel, dim3(N_IMG * H_SZ), dim3(256), 0, stream, x, xt);
  hipLaunchKernelGGL(bitconv_kernel, dim3((C_OUT / 128) * (SP_TOT / 128)), dim3(256),
                     0, stream, wt, xt, zeros, s, bias, out);
}

// Round 2
// 239.755 us; speedup vs baseline: 1.0449x; 1.0449x over previous
//
#include <hip/hip_runtime.h>
#include <hip/hip_bf16.h>

typedef unsigned short ushort_t;

#define N_IMG 32
#define C_IN  128
#define C_OUT 256
#define H_SZ  56
#define W_SZ  56
#define HW_SZ (H_SZ * W_SZ)        // 3136
#define K_TOT (C_IN * 9)           // 1152
#define SP_TOT (N_IMG * HW_SZ)     // 100352

typedef __attribute__((ext_vector_type(8))) short bf16x8;
typedef __attribute__((ext_vector_type(4))) float floatx4;

__device__ __forceinline__ void gl_lds16(const ushort_t* g, ushort_t* l) {
  // 16B per lane, LDS dest = wave-uniform base + lane*16
  __builtin_amdgcn_global_load_lds(
      (const __attribute__((address_space(1))) void*)g,
      (__attribute__((address_space(3))) void*)l, 16, 0, 0);
}

__device__ __forceinline__ ushort_t f2bf(float f) {
  __hip_bfloat16 b = __float2bfloat16(f);
  return *reinterpret_cast<ushort_t*>(&b);
}

// w_q (int32 {-1,0,1}, [co][c][kh][kw]) -> w_t bf16 [co][tap][c]; zero 256B pad page
__global__ void wtrans_kernel(const int* __restrict__ wq, ushort_t* __restrict__ wt,
                              ushort_t* __restrict__ zeros) {
  int tid = threadIdx.x;
  if (blockIdx.x == 0 && tid < 128) zeros[tid] = 0;
  int idx = blockIdx.x * 256 + tid;
  if (idx >= C_OUT * K_TOT) return;
  int co = idx / K_TOT;
  int k  = idx - co * K_TOT;
  int tap = k >> 7;          // k = tap*128 + c
  int c   = k & 127;
  int kh = tap / 3, kw = tap - kh * 3;
  int v = wq[((co * C_IN + c) * 3 + kh) * 3 + kw];
  wt[idx] = f2bf((float)v);
}

// x fp32 NCHW -> x_t bf16 NHWC via 64hw x 64c LDS tiles.
// LDS stride 69 dwords: writes (banks 5c+4f4+j) cover all 32 banks conflict-free;
// reads (banks 10*cpair+hw) hit 16 banks 2-way (free per m136).
#define LDT 69
__global__ __launch_bounds__(256) void xtrans_kernel(const float* __restrict__ x,
                                                     ushort_t* __restrict__ xt) {
  __shared__ float tile[64 * LDT];   // 17664 B
  int b = blockIdx.x;                // n*98 + cg*49 + hwg
  int n = b / 98;
  int r = b - n * 98;
  int cg = r / 49;
  int hwg = r - cg * 49;
  int hw0 = hwg * 64, c0 = cg * 64;
  int t = threadIdx.x;
  int cl = t >> 4;                   // 0..15
  int f4 = t & 15;
  const float* xb = x + ((size_t)(n * C_IN + c0) * HW_SZ + hw0);
#pragma unroll
  for (int p = 0; p < 4; ++p) {
    int c = p * 16 + cl;
    float4 v = *(const float4*)(xb + (size_t)c * HW_SZ + f4 * 4);
    float* dst = &tile[c * LDT + f4 * 4];
    dst[0] = v.x; dst[1] = v.y; dst[2] = v.z; dst[3] = v.w;
  }
  __syncthreads();
  int cp  = t & 31;                  // channel pair
  int hwl = t >> 5;                  // 0..7
  ushort_t* ob = xt + (size_t)(n * HW_SZ + hw0) * C_IN + c0;
#pragma unroll
  for (int p = 0; p < 8; ++p) {
    int hw = p * 8 + hwl;
    unsigned int u = (unsigned int)f2bf(tile[(2 * cp) * LDT + hw]) |
                     ((unsigned int)f2bf(tile[(2 * cp + 1) * LDT + hw]) << 16);
    *(unsigned int*)&ob[(size_t)hw * C_IN + 2 * cp] = u;
  }
}

// Implicit-GEMM conv: C[co][sp] = sum_k A[co][k]*B[k][sp], k = tap*128+c.
// BK=64 (two 64-k stages per tap): 18 barrier pairs vs 36 at BK=32.
__global__ __launch_bounds__(256) void bitconv_kernel(
    const ushort_t* __restrict__ wt, const ushort_t* __restrict__ xt,
    const ushort_t* __restrict__ zeros,
    const float* __restrict__ s, const float* __restrict__ bias,
    float* __restrict__ out) {
  __shared__ ushort_t As[128 * 64];   // 16 KB, [co_local][k_local]
  __shared__ ushort_t Bs[128 * 64];   // 16 KB, [sp_local][k_local]

  // XCD swizzle: co-pair (same sp tile) lands on same XCD under round-robin.
  int d = blockIdx.x;
  int sp_idx = (d >> 4) * 8 + (d & 7);
  int co0 = ((d >> 3) & 1) * 128;
  int sp0 = sp_idx * 128;

  int tid  = threadIdx.x;
  int lane = tid & 63;
  int wid  = tid >> 6;
  int l15  = lane & 15;
  int quad = lane >> 4;
  int lrow8 = lane >> 3;              // 0..7  (row within 8-row staging group)
  int lk8   = (lane & 7) * 8;         // element offset within 64-k row (16B chunks)
  int wave_m = (wid >> 1) * 64;
  int wave_n = (wid & 1) * 64;

  // A staging: wave covers co rows [wid*32, wid*32+32) as 4 groups of 8 rows
  const ushort_t* a_src0 = wt + (size_t)(co0 + wid * 32 + lrow8) * K_TOT + lk8;
  // B rows: per-row spatial decomposition (4 groups of 8 rows)
  int bh[4], bw[4];
  const ushort_t* b_img[4];
#pragma unroll
  for (int j = 0; j < 4; ++j) {
    int sp   = sp0 + wid * 32 + j * 8 + lrow8;
    int nimg = sp / HW_SZ;
    int rem  = sp - nimg * HW_SZ;
    bh[j] = rem / W_SZ;
    bw[j] = rem - bh[j] * W_SZ;
    b_img[j] = xt + (size_t)nimg * HW_SZ * C_IN;
  }

  floatx4 acc[4][4];
#pragma unroll
  for (int mi = 0; mi < 4; ++mi)
#pragma unroll
    for (int ni = 0; ni < 4; ++ni)
      acc[mi][ni] = (floatx4){0.f, 0.f, 0.f, 0.f};

  for (int tap = 0; tap < 9; ++tap) {
    int dh = tap / 3 - 1;
    int dw = tap - (dh + 1) * 3 - 1;
    const ushort_t* bsrc[4];
#pragma unroll
    for (int j = 0; j < 4; ++j) {
      int hh2 = bh[j] + dh, ww2 = bw[j] + dw;
      bool valid = (hh2 >= 0) & (hh2 < H_SZ) & (ww2 >= 0) & (ww2 < W_SZ);
      bsrc[j] = valid ? (b_img[j] + (size_t)(hh2 * W_SZ + ww2) * C_IN + lk8)
                      : (zeros + lk8);
    }
    int ktap = tap * C_IN;
#pragma unroll
    for (int c0 = 0; c0 < C_IN; c0 += 64) {
#pragma unroll
      for (int j = 0; j < 4; ++j) {
        gl_lds16(a_src0 + (size_t)j * 8 * K_TOT + ktap + c0,
                 &As[(wid * 32 + j * 8) * 64]);
        gl_lds16(bsrc[j] + c0, &Bs[(wid * 32 + j * 8) * 64]);
      }
      __syncthreads();
#pragma unroll
      for (int ksub = 0; ksub < 2; ++ksub) {
        bf16x8 af[4], bfv[4];
#pragma unroll
        for (int mi = 0; mi < 4; ++mi)
          af[mi] = *(const bf16x8*)&As[(wave_m + mi * 16 + l15) * 64 +
                                       ksub * 32 + quad * 8];
#pragma unroll
        for (int ni = 0; ni < 4; ++ni)
          bfv[ni] = *(const bf16x8*)&Bs[(wave_n + ni * 16 + l15) * 64 +
                                        ksub * 32 + quad * 8];
#pragma unroll
        for (int mi = 0; mi < 4; ++mi)
#pragma unroll
          for (int ni = 0; ni < 4; ++ni)
            acc[mi][ni] = __builtin_amdgcn_mfma_f32_16x16x32_bf16(
                af[mi], bfv[ni], acc[mi][ni], 0, 0, 0);
      }
      __syncthreads();
    }
  }

  // Epilogue: y = acc*s[co] + bias[co]; C/D layout col(sp)=lane&15, row(co)=quad*4+reg
  int spl_[4], nimg_[4];
#pragma unroll
  for (int ni = 0; ni < 4; ++ni) {
    int sp = sp0 + wave_n + ni * 16 + l15;
    int nimg = sp / HW_SZ;
    nimg_[ni] = nimg;
    spl_[ni]  = sp - nimg * HW_SZ;
  }
#pragma unroll
  for (int mi = 0; mi < 4; ++mi) {
#pragma unroll
    for (int r = 0; r < 4; ++r) {
      int co = co0 + wave_m + mi * 16 + quad * 4 + r;
      float sv = s[co];
      float bv = bias[co];
#pragma unroll
      for (int ni = 0; ni < 4; ++ni) {
        out[((size_t)nimg_[ni] * C_OUT + co) * HW_SZ + spl_[ni]] =
            acc[mi][ni][r] * sv + bv;
      }
    }
  }
}

extern "C" void kernel_launch(void* const* d_in, const int* in_sizes, int n_in,
                              void* d_out, int out_size, void* d_ws, size_t ws_size,
                              hipStream_t stream) {
  const float* x    = (const float*)d_in[0];
  const int*   wq   = (const int*)d_in[1];
  const float* s    = (const float*)d_in[2];
  const float* bias = (const float*)d_in[3];
  float* out = (float*)d_out;

  char* ws = (char*)d_ws;
  ushort_t* zeros = (ushort_t*)ws;                       // 256 B zero page
  ushort_t* wt    = (ushort_t*)(ws + 256);               // 589,824 B
  ushort_t* xt    = (ushort_t*)(ws + 590080);            // 25,690,112 B

  hipLaunchKernelGGL(wtrans_kernel, dim3((C_OUT * K_TOT) / 256), dim3(256), 0, stream,
                     wq, wt, zeros);
  hipLaunchKernelGGL(xtrans_kernel, dim3(N_IMG * 98), dim3(256), 0, stream, x, xt);
  hipLaunchKernelGGL(bitconv_kernel, dim3((C_OUT / 128) * (SP_TOT / 128)), dim3(256),
                     0, stream, wt, xt, zeros, s, bias, out);
}